// Round 7
// baseline (578.853 us; speedup 1.0000x reference)
//
#include <hip/hip_runtime.h>

// DCGRU cell, MI355X. Round 7:
//   cheb_gemm: BARRIER-FREE, LDS-FREE. R2-R6 all plateaued at ~2500+ cyc per
//   barrier-iteration regardless of staging scheme (gload16 / dbuf / skid).
//   Each wave owns a 64x64 output; per k-step it loads its 4 A + 4 B fragments
//   directly global->VGPR in MFMA operand order (lane = row(L&15), k-off
//   (L>>4)*8 — identical register contents to the frag-ordered LDS path, so
//   numerics unchanged) and issues 16 MFMAs. Dist-1 prefetch; k-offset fits
//   the 13-bit immediate. Intra-block 2x fragment reuse is served by L1;
//   cross-block by L2. 528 blocks x 4 waves, no barriers => pure TLP hiding.
//   proj1/proj2: A staged [n][kp] stride 360, 1 ds_read_b128 A-frag, batched
//   B-frag global loads (verified R5/R6).
//   d_out doubles as u-buffer (identical index layout (b*1024+n)*64+o).

typedef unsigned short u16;
typedef unsigned int u32;
typedef short s16x8 __attribute__((ext_vector_type(8)));
typedef float f32x4 __attribute__((ext_vector_type(4)));
typedef u16 u16x4 __attribute__((ext_vector_type(4)));

#define NN 1024
#define NB 64
#define NF 66
#define NCOLS 4224  // NF*NB
#define KPAD 352    // 330 padded to 11*32 (Wt row length)
#define KSTR 360    // proj LDS A row stride

__device__ __forceinline__ u16 f2bf(float f) {
  u32 u = __builtin_bit_cast(u32, f);
  u = (u + 0x7fffu + ((u >> 16) & 1u)) >> 16;  // RNE
  return (u16)u;
}
__device__ __forceinline__ float bf2f(u16 h) {
  u32 u = ((u32)h) << 16;
  return __builtin_bit_cast(float, u);
}

// ---------------- pack kernels ----------------

__global__ __launch_bounds__(256) void pack_supports(
    const float* __restrict__ s0, const float* __restrict__ s1,
    u16* __restrict__ d0, u16* __restrict__ d1) {
  int i = (blockIdx.x * 256 + threadIdx.x) * 4;
  f32x4 a = *(const f32x4*)(s0 + i);
  f32x4 b = *(const f32x4*)(s1 + i);
  u16x4 oa, ob;
  oa.x = f2bf(a.x); oa.y = f2bf(a.y); oa.z = f2bf(a.z); oa.w = f2bf(a.w);
  ob.x = f2bf(b.x); ob.y = f2bf(b.y); ob.z = f2bf(b.z); ob.w = f2bf(b.w);
  *(u16x4*)(d0 + i) = oa;
  *(u16x4*)(d1 + i) = ob;
}

// Wt[o][kp] = W[f*5+m][o], kp = m*66+f, zero-padded kp in [330,352)
__global__ __launch_bounds__(64) void pack_w(
    const float* __restrict__ W, u16* __restrict__ Wt, int ldo) {
  int o = blockIdx.y;
  int kp = blockIdx.x * 64 + threadIdx.x;
  if (kp >= KPAD) return;
  float v = 0.f;
  if (kp < 330) {
    int m = kp / 66;
    int f = kp - m * 66;
    v = W[(f * 5 + m) * ldo + o];
  }
  Wt[(size_t)o * KPAD + kp] = f2bf(v);
}

// rows f=0,1 of X0^T and X0'^T: X0T[f*64+b][n] = inputs[b][2n+f]
__global__ __launch_bounds__(256) void pack_x0_inputs(
    const float* __restrict__ inp, u16* __restrict__ x0t, u16* __restrict__ x0pt) {
  int b = blockIdx.x, t = threadIdx.x;
  int n4 = t * 4;
  const float* src = inp + b * 2048 + n4 * 2;
  f32x4 a = *(const f32x4*)src;
  f32x4 c = *(const f32x4*)(src + 4);
  u16x4 r0, r1;
  r0.x = f2bf(a.x); r0.y = f2bf(a.z); r0.z = f2bf(c.x); r0.w = f2bf(c.z);  // f=0
  r1.x = f2bf(a.y); r1.y = f2bf(a.w); r1.z = f2bf(c.y); r1.w = f2bf(c.w);  // f=1
  size_t o0 = (size_t)(b)*NN + n4;
  size_t o1 = (size_t)(64 + b) * NN + n4;
  *(u16x4*)(x0t + o0) = r0;  *(u16x4*)(x0t + o1) = r1;
  *(u16x4*)(x0pt + o0) = r0; *(u16x4*)(x0pt + o1) = r1;
}

// rows f>=2 of X0^T: X0T[(2+u)*64+b][n] = hx[b][n*64+u]  (64x64 LDS transpose tiles)
__global__ __launch_bounds__(256) void pack_x0_hx(
    const float* __restrict__ hx, u16* __restrict__ x0t) {
  __shared__ float tile[64][65];
  int n0 = blockIdx.x * 64, b = blockIdx.y, t = threadIdx.x;
  int u4 = (t & 15) * 4, r0 = t >> 4;
#pragma unroll
  for (int p = 0; p < 4; p++) {
    int row = p * 16 + r0;
    f32x4 v = *(const f32x4*)(hx + ((size_t)b << 16) + (size_t)(n0 + row) * 64 + u4);
    tile[row][u4] = v.x; tile[row][u4 + 1] = v.y;
    tile[row][u4 + 2] = v.z; tile[row][u4 + 3] = v.w;
  }
  __syncthreads();
  int n4 = (t & 15) * 4, uu0 = t >> 4;
#pragma unroll
  for (int p = 0; p < 4; p++) {
    int u = p * 16 + uu0;
    u16x4 o;
    o.x = f2bf(tile[n4][u]);     o.y = f2bf(tile[n4 + 1][u]);
    o.z = f2bf(tile[n4 + 2][u]); o.w = f2bf(tile[n4 + 3][u]);
    *(u16x4*)&x0t[(size_t)((2 + u) * 64 + b) * NN + n0 + n4] = o;
  }
}

// ---------------- Chebyshev GEMM (barrier-free, LDS-free) ----------------
// C[node][col] = S_z[node][:] . XT_z[col][:], write Xo_z[col][node] (bf16),
// optional fused epilogue: 2*C - Xprev.
// Block = 128 nodes x 128 cols, 4 waves in 2x2; wave = 64x64 via 4x4 MFMA acc.
// Fragments loaded straight global->VGPR (dwordx4, imm k-offset), dist-1
// prefetch, no LDS, no barriers.
__global__ __launch_bounds__(256) void cheb_gemm(
    const u16* __restrict__ S0, const u16* __restrict__ S1,
    const u16* __restrict__ Xi0, const u16* __restrict__ Xi1,
    u16* __restrict__ Xo0, u16* __restrict__ Xo1,
    const u16* __restrict__ Xprev, int use_prev) {
  const int t = threadIdx.x;
  const int lane = t & 63;
  const int w = t >> 6;
  const int n0 = blockIdx.x * 128;  // col tile (XT row)
  const int m0 = blockIdx.y * 128;  // node tile
  const u16* S = blockIdx.z ? S1 : S0;
  const u16* Xi = blockIdx.z ? Xi1 : Xi0;
  u16* Xo = blockIdx.z ? Xo1 : Xo0;

  const int wm = (w >> 1) * 64;  // wave node base within tile
  const int wn = (w & 1) * 64;   // wave col base within tile
  const int frow = lane & 15;
  const int fko = (lane >> 4) * 8;

  // fragment base pointers (A-operand order: lane holds row L&15, k-off (L>>4)*8)
  const u16* pA[4];
  const u16* pB[4];
#pragma unroll
  for (int i = 0; i < 4; i++)
    pA[i] = S + (size_t)(m0 + wm + i * 16 + frow) * NN + fko;
#pragma unroll
  for (int j = 0; j < 4; j++)
    pB[j] = Xi + (size_t)(n0 + wn + j * 16 + frow) * NN + fko;

  f32x4 acc[4][4];
#pragma unroll
  for (int i = 0; i < 4; i++)
#pragma unroll
    for (int j = 0; j < 4; j++) acc[i][j] = f32x4{0.f, 0.f, 0.f, 0.f};

  s16x8 a0[4], b0[4], a1[4], b1[4];
#pragma unroll
  for (int i = 0; i < 4; i++) a0[i] = *(const s16x8*)(pA[i] + 0);
#pragma unroll
  for (int j = 0; j < 4; j++) b0[j] = *(const s16x8*)(pB[j] + 0);

  for (int k0 = 0; k0 < 1024; k0 += 64) {
    // prefetch k0+32
#pragma unroll
    for (int i = 0; i < 4; i++) a1[i] = *(const s16x8*)(pA[i] + k0 + 32);
#pragma unroll
    for (int j = 0; j < 4; j++) b1[j] = *(const s16x8*)(pB[j] + k0 + 32);
    // compute k0
#pragma unroll
    for (int i = 0; i < 4; i++)
#pragma unroll
      for (int j = 0; j < 4; j++)
        acc[i][j] = __builtin_amdgcn_mfma_f32_16x16x32_bf16(a0[i], b0[j], acc[i][j], 0, 0, 0);
    // prefetch k0+64 (wrap: last iter reloads k=0, discarded, L1-hot)
    const int kn = (k0 + 64) & 1023;
#pragma unroll
    for (int i = 0; i < 4; i++) a0[i] = *(const s16x8*)(pA[i] + kn);
#pragma unroll
    for (int j = 0; j < 4; j++) b0[j] = *(const s16x8*)(pB[j] + kn);
    // compute k0+32
#pragma unroll
    for (int i = 0; i < 4; i++)
#pragma unroll
      for (int j = 0; j < 4; j++)
        acc[i][j] = __builtin_amdgcn_mfma_f32_16x16x32_bf16(a1[i], b1[j], acc[i][j], 0, 0, 0);
  }

  // C/D layout: col = lane&15, row = (lane>>4)*4 + reg
  const int fr = lane & 15;
  const int nr0 = (lane >> 4) * 4;
#pragma unroll
  for (int i = 0; i < 4; i++) {
    const int node = m0 + wm + i * 16 + nr0;
#pragma unroll
    for (int j = 0; j < 4; j++) {
      const int colg = n0 + wn + j * 16 + fr;
      size_t off = (size_t)colg * NN + node;
      f32x4 c = acc[i][j];
      if (use_prev) {
        u16x4 p = *(const u16x4*)&Xprev[off];
        c.x = 2.f * c.x - bf2f(p.x);
        c.y = 2.f * c.y - bf2f(p.y);
        c.z = 2.f * c.z - bf2f(p.z);
        c.w = 2.f * c.w - bf2f(p.w);
      }
      u16x4 o;
      o.x = f2bf(c.x); o.y = f2bf(c.y); o.z = f2bf(c.z); o.w = f2bf(c.w);
      *(u16x4*)&Xo[off] = o;
    }
  }
}

// ---------------- projections (MFMA) ----------------

// stage activation slice into LDS A[n][kp], row stride KSTR, kp = mm*66+f.
__device__ __forceinline__ void stage_x(u32* A32, const u16* __restrict__ X, int mm,
                                        int b, int n0, int t) {
  for (int idx = t; idx < 33 * 64; idx += 256) {
    int p = idx >> 6, n = idx & 63, f = 2 * p;
    u32 v0 = X[(size_t)(f * 64 + b) * NN + n0 + n];
    u32 v1 = X[(size_t)((f + 1) * 64 + b) * NN + n0 + n];
    A32[n * (KSTR / 2) + mm * 33 + p] = v0 | (v1 << 16);
  }
}

// zero kp in [330, 352) ONLY (MFMA loop reads kp<=351; kp>=360 is next row!)
__device__ __forceinline__ void zero_pad_rows(u16* A, int t) {
  for (int idx = t; idx < 64 * 22; idx += 256) {
    int n = idx / 22, q = idx % 22;
    A[n * KSTR + 330 + q] = 0;
  }
}

// gconv1 projection: [64n x 330] @ Wt1^T -> 128 outs; sigmoid; r*hx -> X0'^T; u -> uout.
__global__ __launch_bounds__(256) void proj1(
    const u16* __restrict__ X0, const u16* __restrict__ X1, const u16* __restrict__ X2,
    const u16* __restrict__ X3, const u16* __restrict__ X4,
    const u16* __restrict__ Wt, const float* __restrict__ bias,
    const float* __restrict__ hx, u16* __restrict__ X0p, float* __restrict__ uout) {
  __shared__ u16 A[64 * KSTR + 16];
  const int t = threadIdx.x;
  const int n0 = blockIdx.x * 64;
  const int b = blockIdx.y;
  u32* A32 = (u32*)A;
  stage_x(A32, X0, 0, b, n0, t);
  stage_x(A32, X1, 1, b, n0, t);
  stage_x(A32, X2, 2, b, n0, t);
  stage_x(A32, X3, 3, b, n0, t);
  stage_x(A32, X4, 4, b, n0, t);
  zero_pad_rows(A, t);
  __syncthreads();

  const int lane = t & 63;
  const int w = t >> 6;
  const int fr = lane & 15;
  const int ko8 = (lane >> 4) * 8;

  f32x4 acc[8];
#pragma unroll
  for (int j = 0; j < 8; j++) acc[j] = f32x4{0.f, 0.f, 0.f, 0.f};

#pragma unroll 2
  for (int kc = 0; kc < KPAD; kc += 32) {
    s16x8 af = *(const s16x8*)&A[(w * 16 + fr) * KSTR + kc + ko8];
    s16x8 bf[8];
#pragma unroll
    for (int j = 0; j < 8; j++)
      bf[j] = *(const s16x8*)&Wt[(size_t)(j * 16 + fr) * KPAD + kc + ko8];
#pragma unroll
    for (int j = 0; j < 8; j++)
      acc[j] = __builtin_amdgcn_mfma_f32_16x16x32_bf16(af, bf[j], acc[j], 0, 0, 0);
  }

  // D layout: col(o within sub) = lane&15, row(n within sub) = (lane>>4)*4 + reg
  const int nl0 = (lane >> 4) * 4;
  const int n = n0 + w * 16 + nl0;  // + reg
#pragma unroll
  for (int j = 0; j < 8; j++) {
    const int o = j * 16 + fr;
    const float bs = bias[o];
    f32x4 v;
    v.x = 1.f / (1.f + __expf(-(acc[j].x + bs)));
    v.y = 1.f / (1.f + __expf(-(acc[j].y + bs)));
    v.z = 1.f / (1.f + __expf(-(acc[j].z + bs)));
    v.w = 1.f / (1.f + __expf(-(acc[j].w + bs)));
    if (o < 64) {  // r-part -> X0'^T row (2+o)*64+b, times hx
      const float* hxp = hx + ((size_t)b << 16) + (size_t)n * 64 + o;
      u16x4 s;
      s.x = f2bf(v.x * hxp[0 * 64]);
      s.y = f2bf(v.y * hxp[1 * 64]);
      s.z = f2bf(v.z * hxp[2 * 64]);
      s.w = f2bf(v.w * hxp[3 * 64]);
      *(u16x4*)&X0p[(size_t)((2 + o) * 64 + b) * NN + n] = s;
    } else {  // u-part -> uout (d_out scratch)
      float* up = uout + (((size_t)b << 10) + n) * 64 + (o - 64);
      up[0 * 64] = v.x; up[1 * 64] = v.y; up[2 * 64] = v.z; up[3 * 64] = v.w;
    }
  }
}

// gconv2 projection: tanh + GRU blend. uin aliases out (same layout) - no restrict.
__global__ __launch_bounds__(256) void proj2(
    const u16* __restrict__ X0, const u16* __restrict__ X1, const u16* __restrict__ X2,
    const u16* __restrict__ X3, const u16* __restrict__ X4,
    const u16* __restrict__ Wt, const float* __restrict__ bias,
    const float* __restrict__ hx, const float* uin, float* out) {
  __shared__ u16 A[64 * KSTR + 16];
  const int t = threadIdx.x;
  const int n0 = blockIdx.x * 64;
  const int b = blockIdx.y;
  u32* A32 = (u32*)A;
  stage_x(A32, X0, 0, b, n0, t);
  stage_x(A32, X1, 1, b, n0, t);
  stage_x(A32, X2, 2, b, n0, t);
  stage_x(A32, X3, 3, b, n0, t);
  stage_x(A32, X4, 4, b, n0, t);
  zero_pad_rows(A, t);
  __syncthreads();

  const int lane = t & 63;
  const int w = t >> 6;
  const int fr = lane & 15;
  const int ko8 = (lane >> 4) * 8;

  f32x4 acc[4];
#pragma unroll
  for (int j = 0; j < 4; j++) acc[j] = f32x4{0.f, 0.f, 0.f, 0.f};

#pragma unroll 2
  for (int kc = 0; kc < KPAD; kc += 32) {
    s16x8 af = *(const s16x8*)&A[(w * 16 + fr) * KSTR + kc + ko8];
    s16x8 bf[4];
#pragma unroll
    for (int j = 0; j < 4; j++)
      bf[j] = *(const s16x8*)&Wt[(size_t)(j * 16 + fr) * KPAD + kc + ko8];
#pragma unroll
    for (int j = 0; j < 4; j++)
      acc[j] = __builtin_amdgcn_mfma_f32_16x16x32_bf16(af, bf[j], acc[j], 0, 0, 0);
  }

  const int nl0 = (lane >> 4) * 4;
  const int n = n0 + w * 16 + nl0;  // + reg
#pragma unroll
  for (int j = 0; j < 4; j++) {
    const int o = j * 16 + fr;
    const float bs = bias[o];
    const size_t base = (((size_t)b << 10) + n) * 64 + o;  // + reg*64
    float c0 = tanhf(acc[j].x + bs);
    float c1 = tanhf(acc[j].y + bs);
    float c2 = tanhf(acc[j].z + bs);
    float c3 = tanhf(acc[j].w + bs);
    float u0 = uin[base + 0 * 64], u1 = uin[base + 1 * 64];
    float u2 = uin[base + 2 * 64], u3 = uin[base + 3 * 64];
    float h0 = hx[base + 0 * 64], h1 = hx[base + 1 * 64];
    float h2 = hx[base + 2 * 64], h3 = hx[base + 3 * 64];
    out[base + 0 * 64] = u0 * h0 + (1.f - u0) * c0;
    out[base + 1 * 64] = u1 * h1 + (1.f - u1) * c1;
    out[base + 2 * 64] = u2 * h2 + (1.f - u2) * c2;
    out[base + 3 * 64] = u3 * h3 + (1.f - u3) * c3;
  }
}

// ---------------- launch ----------------

extern "C" void kernel_launch(void* const* d_in, const int* in_sizes, int n_in,
                              void* d_out, int out_size, void* d_ws, size_t ws_size,
                              hipStream_t stream) {
  (void)in_sizes; (void)n_in; (void)out_size; (void)ws_size;
  const float* inp = (const float*)d_in[0];
  const float* hx  = (const float*)d_in[1];
  const float* s0  = (const float*)d_in[2];
  const float* s1  = (const float*)d_in[3];
  const float* Wo  = (const float*)d_in[4];
  const float* bo  = (const float*)d_in[5];
  const float* Wu  = (const float*)d_in[6];
  const float* bu  = (const float*)d_in[7];
  float* out = (float*)d_out;

  char* p = (char*)d_ws;
  u16* Sb0 = (u16*)p; p += (size_t)NN * NN * 2;
  u16* Sb1 = (u16*)p; p += (size_t)NN * NN * 2;
  const size_t xbytes = (size_t)NCOLS * NN * 2;
  u16* X0T = (u16*)p; p += xbytes;
  u16* X1T = (u16*)p; p += xbytes;
  u16* X2T = (u16*)p; p += xbytes;
  u16* X3T = (u16*)p; p += xbytes;
  u16* X4T = (u16*)p; p += xbytes;
  u16* X0P = (u16*)p; p += xbytes;
  u16* Wt1 = (u16*)p; p += (size_t)128 * KPAD * 2;
  u16* Wt2 = (u16*)p; p += (size_t)64 * KPAD * 2;
  // total ws use: 4 MB + 6*8.25 MB + ~132 KB

  pack_supports<<<dim3(1024), dim3(256), 0, stream>>>(s0, s1, Sb0, Sb1);
  pack_w<<<dim3(6, 128), dim3(64), 0, stream>>>(Wo, Wt1, 128);
  pack_w<<<dim3(6, 64), dim3(64), 0, stream>>>(Wu, Wt2, 64);
  pack_x0_inputs<<<dim3(64), dim3(256), 0, stream>>>(inp, X0T, X0P);
  pack_x0_hx<<<dim3(16, 64), dim3(256), 0, stream>>>(hx, X0T);
  // gconv1 Chebyshev: X1=S0 X0, X3=S1 X0 ; X2=2 S0 X1 - X0, X4=2 S1 X3 - X0
  cheb_gemm<<<dim3(33, 8, 2), dim3(256), 0, stream>>>(Sb0, Sb1, X0T, X0T, X1T, X3T,
                                                      (const u16*)nullptr, 0);
  cheb_gemm<<<dim3(33, 8, 2), dim3(256), 0, stream>>>(Sb0, Sb1, X1T, X3T, X2T, X4T, X0T, 1);
  proj1<<<dim3(16, 64), dim3(256), 0, stream>>>(X0T, X1T, X2T, X3T, X4T, Wt1, bo, hx, X0P, out);
  // gconv2 Chebyshev on X0' (reuse X1..X4 buffers)
  cheb_gemm<<<dim3(33, 8, 2), dim3(256), 0, stream>>>(Sb0, Sb1, X0P, X0P, X1T, X3T,
                                                      (const u16*)nullptr, 0);
  cheb_gemm<<<dim3(33, 8, 2), dim3(256), 0, stream>>>(Sb0, Sb1, X1T, X3T, X2T, X4T, X0P, 1);
  proj2<<<dim3(16, 64), dim3(256), 0, stream>>>(X0P, X1T, X2T, X3T, X4T, Wt2, bu, hx, out, out);
}